// Round 11
// baseline (2171.070 us; speedup 1.0000x reference)
//
#include <hip/hip_runtime.h>

// ---- problem dims ----
#define NN 20000
#define NE 640000
#define FF 128
#define H1 64
#define H2 32
#define RR 65
#define BQ 4096
#define NR (NN*RR)

#define DBLK 128              // dsts per block
#define NBLK 157              // ceil(20000/128)
#define NB (NBLK*RR)          // 10205 bins
#define NBPAD 10240

typedef __attribute__((ext_vector_type(8))) short bhalf8;   // 8 bf16 (4 VGPRs)
typedef __attribute__((ext_vector_type(4))) float f32x4;
#define MFMA16(a, b, c) __builtin_amdgcn_mfma_f32_16x16x32_bf16(a, b, c, 0, 0, 0)

__device__ __forceinline__ unsigned short f2bf(float f) {
  unsigned int u = __float_as_uint(f);
  unsigned int r = (u + 0x7fffu + ((u >> 16) & 1u)) >> 16;   // RNE
  return (unsigned short)r;
}
__device__ __forceinline__ float bf2f(unsigned short u) {
  return __uint_as_float((unsigned)u << 16);
}

// ===================== histogram: (dst,rel) cnt + (dstblock,rel) bin cnt ==========
__global__ __launch_bounds__(256) void k_hist(
    const int* __restrict__ ei, const int* __restrict__ etA, const int* __restrict__ etB,
    int* __restrict__ cntA, int* __restrict__ cntB,
    int* __restrict__ binCntA, int* __restrict__ binCntB) {
  int e = blockIdx.x * blockDim.x + threadIdx.x;
  if (e >= NE) return;
  int d = ei[NE + e];
  int ta = etA[e], tb = etB[e];
  atomicAdd(&cntA[(size_t)d * RR + ta], 1);
  atomicAdd(&cntB[(size_t)d * RR + tb], 1);
  atomicAdd(&binCntA[(d >> 7) * RR + ta], 1);
  atomicAdd(&binCntB[(d >> 7) * RR + tb], 1);
}

// ===================== exclusive scan over 10205 bins (both streams, 1 block) ======
__global__ __launch_bounds__(256) void k_prefixB(
    const int* __restrict__ cA, int* __restrict__ sA, int* __restrict__ uA,
    const int* __restrict__ cB, int* __restrict__ sB, int* __restrict__ uB) {
  __shared__ int ps[256];
  __shared__ int pb[257];
  int t = threadIdx.x;
  int c0 = t * 40;
  int c1 = (c0 + 40 < NB) ? (c0 + 40) : NB;
  // stream A
  {
    int s = 0;
    for (int i = c0; i < c1; ++i) s += cA[i];
    ps[t] = s;
    __syncthreads();
    if (t == 0) { int a = 0; for (int i = 0; i < 256; ++i) { pb[i] = a; a += ps[i]; } }
    __syncthreads();
    int run = pb[t];
    for (int i = c0; i < c1; ++i) { sA[i] = run; uA[i] = run; run += cA[i]; }
    __syncthreads();
  }
  // stream B
  {
    int s = 0;
    for (int i = c0; i < c1; ++i) s += cB[i];
    ps[t] = s;
    __syncthreads();
    if (t == 0) { int a = 0; for (int i = 0; i < 256; ++i) { pb[i] = a; a += ps[i]; } }
    __syncthreads();
    int run = pb[t];
    for (int i = c0; i < c1; ++i) { sB[i] = run; uB[i] = run; run += cB[i]; }
  }
}

// ===================== scatter edges into (dstblock,rel) bins with packed meta =====
// m = src | dstLocal<<20 ; iv = 1/cnt(dst,rel)
__global__ __launch_bounds__(256) void k_scatter2(
    const int* __restrict__ ei, const int* __restrict__ etA, const int* __restrict__ etB,
    const int* __restrict__ cntA, const int* __restrict__ cntB,
    int* __restrict__ binCurA, int* __restrict__ binCurB,
    int* __restrict__ mA, float* __restrict__ ivA,
    int* __restrict__ mB, float* __restrict__ ivB) {
  int e = blockIdx.x * blockDim.x + threadIdx.x;
  if (e >= NE) return;
  int s = ei[e], d = ei[NE + e];
  int mm = s | ((d & (DBLK - 1)) << 20);
  {
    int t = etA[e];
    int p = atomicAdd(&binCurA[(d >> 7) * RR + t], 1);
    mA[p] = mm;
    ivA[p] = 1.0f / (float)cntA[(size_t)d * RR + t];
  }
  {
    int t = etB[e];
    int p = atomicAdd(&binCurB[(d >> 7) * RR + t], 1);
    mB[p] = mm;
    ivB[p] = 1.0f / (float)cntB[(size_t)d * RR + t];
  }
}

// ===================== fp32 -> bf16 conversion for x_o and x_a ====================
__global__ __launch_bounds__(256) void k_cvt2(const float4* __restrict__ inA,
                                              const float4* __restrict__ inB,
                                              uint4* __restrict__ outA,
                                              uint4* __restrict__ outB, int n8) {
  int i = blockIdx.x * blockDim.x + threadIdx.x;
  if (i >= 2 * n8) return;
  const float4* in = (i < n8) ? inA : inB;
  uint4* out = (i < n8) ? outA : outB;
  int j = (i < n8) ? i : i - n8;
  float4 a = in[2 * j], b = in[2 * j + 1];
  uint4 o;
  o.x = (unsigned)f2bf(a.x) | ((unsigned)f2bf(a.y) << 16);
  o.y = (unsigned)f2bf(a.z) | ((unsigned)f2bf(a.w) << 16);
  o.z = (unsigned)f2bf(b.x) | ((unsigned)f2bf(b.y) << 16);
  o.w = (unsigned)f2bf(b.z) | ((unsigned)f2bf(b.w) << 16);
  out[j] = o;
}

// ===================== W1 -> bf16 B-fragments =====================
__global__ __launch_bounds__(256) void k_wprep1(const float* __restrict__ W,
                                                unsigned short* __restrict__ Wf) {
  int r = blockIdx.x;
  int lane = threadIdx.x & 63, w = threadIdx.x >> 6;
#pragma unroll
  for (int s4 = 0; s4 < 4; ++s4) {
    int slot = w * 4 + s4;
    int ks = slot >> 2, n = slot & 3;
    int krow = ks * 32 + ((lane >> 4) << 3);
    int colo = n * 16 + (lane & 15);
    unsigned short* o = Wf + (((size_t)r * 16 + slot) * 64 + lane) * 8;
#pragma unroll
    for (int j = 0; j < 8; ++j)
      o[j] = f2bf(W[((size_t)r * FF + krow + j) * H1 + colo]);
  }
}

// ===================== W2 -> bf16 B-fragments =====================
__global__ __launch_bounds__(256) void k_wprep2(const float* __restrict__ W,
                                                unsigned short* __restrict__ Wf) {
  int r = blockIdx.x;
  int lane = threadIdx.x & 63, slot = threadIdx.x >> 6;
  int ks = slot >> 1, n = slot & 1;
  int krow = ks * 32 + ((lane >> 4) << 3);
  int colo = n * 16 + (lane & 15);
  unsigned short* o = Wf + (((size_t)r * 4 + slot) * 64 + lane) * 8;
#pragma unroll
  for (int j = 0; j < 8; ++j)
    o[j] = f2bf(W[((size_t)r * H1 + krow + j) * H2 + colo]);
}

// ===================== layer-1 root terms -> bf16 =====================
__global__ __launch_bounds__(256) void k_root1(
    const float* __restrict__ xo, const float* __restrict__ xa,
    const float* __restrict__ rt, const float* __restrict__ b,
    unsigned short* __restrict__ rO, unsigned short* __restrict__ rA) {
  int lane = threadIdx.x & 63;
  int n = (blockIdx.x * blockDim.x + threadIdx.x) >> 6;
  if (n >= NN) return;
  const float4* xo4 = (const float4*)(xo + (size_t)n * FF);
  const float4* xa4 = (const float4*)(xa + (size_t)n * FF);
  float so = b[lane], sa = so;
#pragma unroll
  for (int j = 0; j < FF / 4; ++j) {
    float vo[4], va[4];
    *(float4*)vo = xo4[j];
    *(float4*)va = xa4[j];
#pragma unroll
    for (int t = 0; t < 4; ++t) {
      float wv = rt[(4 * j + t) * H1 + lane];
      so = fmaf(vo[t], wv, so);
      sa = fmaf(va[t], wv, sa);
    }
  }
  rO[(size_t)n * H1 + lane] = f2bf(so);
  rA[(size_t)n * H1 + lane] = f2bf(sa);
}

// ===================== layer-1 edge GEMM + LDS fp32 aggregation ====================
// Block owns 128 dsts; fp32 tile yT[NIN][128][64] in LDS. Per relation bin: the
// proven 16-edge MFMA groups (W_r frags in VGPRs); scatter = LDS atomicAdd
// (ds_add_f32 — bank-parallel, kills the L2 atomic-ALU wall of r8/r9).
// Epilogue: + root (bf16) , relu, bf16 store — one plain write per output.
template <int NIN>
__global__ __launch_bounds__(512, 1) void k_edgeL1(
    const int* __restrict__ mP, const float* __restrict__ ivP,
    const int* __restrict__ binStart, const int* __restrict__ binCnt,
    const unsigned short* __restrict__ Wf,
    const unsigned short* __restrict__ xA16, const unsigned short* __restrict__ xB16,
    const unsigned short* __restrict__ root0, const unsigned short* __restrict__ root1,
    unsigned short* __restrict__ y0, unsigned short* __restrict__ y1) {
  __shared__ float yT[NIN][DBLK][H1];     // 32KB per tile
  const int b = blockIdx.x;
  const int tid = threadIdx.x;
  {
    float4* p = (float4*)yT;
    for (int i = tid; i < NIN * DBLK * H1 / 4; i += 512) p[i] = float4{0.f, 0.f, 0.f, 0.f};
  }
  __syncthreads();
  const int lane = tid & 63;
  const int wv = tid >> 6;                // 0..7
  const int cg = lane >> 4;
  const int col = lane & 15;
  const int row0 = cg << 2;

  for (int rel = 0; rel < RR; ++rel) {
    const int bin = b * RR + rel;
    const int bs = binStart[bin];
    const int cnt = binCnt[bin];
    const int ng = (cnt + 15) >> 4;
    if (ng <= wv) continue;               // this wave has no group for this relation
    bhalf8 wb[16];
    {
      const bhalf8* wf = (const bhalf8*)Wf + ((size_t)rel * 16) * 64 + lane;
#pragma unroll
      for (int s = 0; s < 16; ++s) wb[s] = wf[(size_t)s * 64];
    }
    for (int G = wv; G < ng; G += 8) {
      const int base = bs + (G << 4);
      const int lim = cnt - (G << 4);
      const int off = base + ((col < lim) ? col : 0);
      const int m = mP[off];
      const float iv = (col < lim) ? ivP[off] : 0.f;
      const int src = m & 0xFFFFF;
      const int dl = ((unsigned)m) >> 20;
      const int dl0 = __shfl(dl, row0),     dl1 = __shfl(dl, row0 + 1),
                dl2 = __shfl(dl, row0 + 2), dl3 = __shfl(dl, row0 + 3);
      const float i0 = __shfl(iv, row0),     i1 = __shfl(iv, row0 + 1),
                  i2 = __shfl(iv, row0 + 2), i3 = __shfl(iv, row0 + 3);
#pragma unroll
      for (int in = 0; in < NIN; ++in) {
        const unsigned short* xp = (in == 0) ? xA16 : xB16;
        const bhalf8* xr = (const bhalf8*)xp + ((size_t)src << 4);
        bhalf8 a0 = xr[cg], a1 = xr[4 + cg], a2 = xr[8 + cg], a3 = xr[12 + cg];
        f32x4 c0 = {0.f,0.f,0.f,0.f}, c1 = c0, c2 = c0, c3 = c0;
        c0 = MFMA16(a0, wb[0], c0);  c1 = MFMA16(a0, wb[1], c1);
        c2 = MFMA16(a0, wb[2], c2);  c3 = MFMA16(a0, wb[3], c3);
        c0 = MFMA16(a1, wb[4], c0);  c1 = MFMA16(a1, wb[5], c1);
        c2 = MFMA16(a1, wb[6], c2);  c3 = MFMA16(a1, wb[7], c3);
        c0 = MFMA16(a2, wb[8], c0);  c1 = MFMA16(a2, wb[9], c1);
        c2 = MFMA16(a2, wb[10], c2); c3 = MFMA16(a2, wb[11], c3);
        c0 = MFMA16(a3, wb[12], c0); c1 = MFMA16(a3, wb[13], c1);
        c2 = MFMA16(a3, wb[14], c2); c3 = MFMA16(a3, wb[15], c3);
        const f32x4 cc[4] = {c0, c1, c2, c3};
#pragma unroll
        for (int n = 0; n < 4; ++n) {
          atomicAdd(&yT[in][dl0][n * 16 + col], cc[n][0] * i0);
          atomicAdd(&yT[in][dl1][n * 16 + col], cc[n][1] * i1);
          atomicAdd(&yT[in][dl2][n * 16 + col], cc[n][2] * i2);
          atomicAdd(&yT[in][dl3][n * 16 + col], cc[n][3] * i3);
        }
      }
    }
  }
  __syncthreads();
  const int dBase = b * DBLK;
  for (int i = tid; i < DBLK * H1; i += 512) {
    int dl = i >> 6, c = i & 63;
    int d = dBase + dl;
    if (d < NN) {
      size_t o = (size_t)d * H1 + c;
      float v0 = bf2f(root0[o]) + yT[0][dl][c];
      y0[o] = f2bf(fmaxf(v0, 0.f));
      if constexpr (NIN == 2) {
        float v1 = bf2f(root1[o]) + yT[1][dl][c];
        y1[o] = f2bf(fmaxf(v1, 0.f));
      }
    }
  }
}

// ===================== layer-2 root terms (bf16 in/out), 3 fused =====================
__global__ __launch_bounds__(256) void k_root2x3(
    const unsigned short* __restrict__ x1o, const unsigned short* __restrict__ x1a,
    const unsigned short* __restrict__ x1aa,
    const float* __restrict__ rt, const float* __restrict__ b,
    unsigned short* __restrict__ y0, unsigned short* __restrict__ y1,
    unsigned short* __restrict__ y2) {
  int i = blockIdx.x * blockDim.x + threadIdx.x;
  if (i >= NN * H2) return;
  int o = i & (H2 - 1);
  int n = i >> 5;
  const uint2* p0 = (const uint2*)(x1o + (size_t)n * H1);
  const uint2* p1 = (const uint2*)(x1a + (size_t)n * H1);
  const uint2* p2 = (const uint2*)(x1aa + (size_t)n * H1);
  float s0 = b[o], s1 = s0, s2 = s0;
#pragma unroll
  for (int j = 0; j < 16; ++j) {
    uint2 u0 = p0[j], u1 = p1[j], u2 = p2[j];
#pragma unroll
    for (int t = 0; t < 4; ++t) {
      unsigned w0 = (t < 2) ? u0.x : u0.y;
      unsigned w1 = (t < 2) ? u1.x : u1.y;
      unsigned w2 = (t < 2) ? u2.x : u2.y;
      int sh = (t & 1) * 16;
      float wv = rt[(4 * j + t) * H2 + o];
      s0 = fmaf(bf2f((unsigned short)(w0 >> sh)), wv, s0);
      s1 = fmaf(bf2f((unsigned short)(w1 >> sh)), wv, s1);
      s2 = fmaf(bf2f((unsigned short)(w2 >> sh)), wv, s2);
    }
  }
  y0[i] = f2bf(s0); y1[i] = f2bf(s1); y2[i] = f2bf(s2);
}

// ===================== layer-2 edge GEMM + LDS aggregation =====================
template <int NIN>
__global__ __launch_bounds__(512, 1) void k_edgeL2(
    const int* __restrict__ mP, const float* __restrict__ ivP,
    const int* __restrict__ binStart, const int* __restrict__ binCnt,
    const unsigned short* __restrict__ Wf,
    const unsigned short* __restrict__ xA16, const unsigned short* __restrict__ xB16,
    const unsigned short* __restrict__ root0, const unsigned short* __restrict__ root1,
    unsigned short* __restrict__ y0, unsigned short* __restrict__ y1,
    float* __restrict__ f32out) {
  __shared__ float yT[NIN][DBLK][H2];     // 16KB per tile
  const int b = blockIdx.x;
  const int tid = threadIdx.x;
  {
    float4* p = (float4*)yT;
    for (int i = tid; i < NIN * DBLK * H2 / 4; i += 512) p[i] = float4{0.f, 0.f, 0.f, 0.f};
  }
  __syncthreads();
  const int lane = tid & 63;
  const int wv = tid >> 6;
  const int cg = lane >> 4;
  const int col = lane & 15;
  const int row0 = cg << 2;

  for (int rel = 0; rel < RR; ++rel) {
    const int bin = b * RR + rel;
    const int bs = binStart[bin];
    const int cnt = binCnt[bin];
    const int ng = (cnt + 15) >> 4;
    if (ng <= wv) continue;
    bhalf8 wb[4];
    {
      const bhalf8* wf = (const bhalf8*)Wf + ((size_t)rel * 4) * 64 + lane;
#pragma unroll
      for (int s = 0; s < 4; ++s) wb[s] = wf[(size_t)s * 64];
    }
    for (int G = wv; G < ng; G += 8) {
      const int base = bs + (G << 4);
      const int lim = cnt - (G << 4);
      const int off = base + ((col < lim) ? col : 0);
      const int m = mP[off];
      const float iv = (col < lim) ? ivP[off] : 0.f;
      const int src = m & 0xFFFFF;
      const int dl = ((unsigned)m) >> 20;
      const int dl0 = __shfl(dl, row0),     dl1 = __shfl(dl, row0 + 1),
                dl2 = __shfl(dl, row0 + 2), dl3 = __shfl(dl, row0 + 3);
      const float i0 = __shfl(iv, row0),     i1 = __shfl(iv, row0 + 1),
                  i2 = __shfl(iv, row0 + 2), i3 = __shfl(iv, row0 + 3);
#pragma unroll
      for (int in = 0; in < NIN; ++in) {
        const unsigned short* xp = (in == 0) ? xA16 : xB16;
        const bhalf8* xr = (const bhalf8*)xp + ((size_t)src << 3);
        bhalf8 a0 = xr[cg], a1 = xr[4 + cg];
        f32x4 c0 = {0.f,0.f,0.f,0.f}, c1 = c0;
        c0 = MFMA16(a0, wb[0], c0); c1 = MFMA16(a0, wb[1], c1);
        c0 = MFMA16(a1, wb[2], c0); c1 = MFMA16(a1, wb[3], c1);
        const f32x4 cc[2] = {c0, c1};
#pragma unroll
        for (int n = 0; n < 2; ++n) {
          atomicAdd(&yT[in][dl0][n * 16 + col], cc[n][0] * i0);
          atomicAdd(&yT[in][dl1][n * 16 + col], cc[n][1] * i1);
          atomicAdd(&yT[in][dl2][n * 16 + col], cc[n][2] * i2);
          atomicAdd(&yT[in][dl3][n * 16 + col], cc[n][3] * i3);
        }
      }
    }
  }
  __syncthreads();
  const int dBase = b * DBLK;
  for (int i = tid; i < DBLK * H2; i += 512) {
    int dl = i >> 5, c = i & 31;
    int d = dBase + dl;
    if (d < NN) {
      size_t o = (size_t)d * H2 + c;
      float v0 = bf2f(root0[o]) + yT[0][dl][c];
      y0[o] = f2bf(v0);
      if (f32out) f32out[o] = v0;
      if constexpr (NIN == 2) {
        float v1 = bf2f(root1[o]) + yT[1][dl][c];
        y1[o] = f2bf(v1);
      }
    }
  }
}

// ===================== column sum of x2_o (fp32) -> hacc[32] =====================
__global__ __launch_bounds__(256) void k_colsum(const float* __restrict__ x2o,
                                                float* __restrict__ hacc) {
  int tid = threadIdx.x;
  int col = tid & 31;
  int rgrp = blockIdx.x * (blockDim.x >> 5) + (tid >> 5);
  int nth = gridDim.x * (blockDim.x >> 5);
  float s = 0.f;
  for (int n = rgrp; n < NN; n += nth) s += x2o[(size_t)n * H2 + col];
  unsafeAtomicAdd(&hacc[col], s);
}

// ===================== h_os = sigmoid(mean); v = disc_w @ h_os =====================
__global__ __launch_bounds__(64) void k_disc(const float* __restrict__ hacc,
                                             const float* __restrict__ dw,
                                             float* __restrict__ vout) {
  __shared__ float hos[H2];
  int t = threadIdx.x;
  if (t < H2) hos[t] = 1.0f / (1.0f + expf(-hacc[t] / (float)NN));
  __syncthreads();
  if (t < H2) {
    float s = 0.f;
#pragma unroll
    for (int k = 0; k < H2; ++k) s = fmaf(dw[t * H2 + k], hos[k], s);
    vout[t] = s;
  }
}

// ===================== ret_os / ret_os_a (bf16 x2 inputs) =====================
__global__ __launch_bounds__(256) void k_ret(
    const unsigned short* __restrict__ x2o, const unsigned short* __restrict__ x2oa,
    const unsigned short* __restrict__ x2oaa,
    const float* __restrict__ v, const float* __restrict__ db,
    float* __restrict__ ros, float* __restrict__ rosa) {
  int n = blockIdx.x * blockDim.x + threadIdx.x;
  if (n >= NN) return;
  const uint2* a2 = (const uint2*)(x2o + (size_t)n * H2);
  const uint2* b2 = (const uint2*)(x2oa + (size_t)n * H2);
  const uint2* c2 = (const uint2*)(x2oaa + (size_t)n * H2);
  const float4* v4 = (const float4*)v;
  float r0 = 0.f, r1 = 0.f, r2 = 0.f;
#pragma unroll
  for (int j = 0; j < 8; ++j) {
    uint2 ua = a2[j], ub = b2[j], uc = c2[j];
    float4 vv = v4[j];
    r0 += bf2f((unsigned short)ua.x) * vv.x + bf2f((unsigned short)(ua.x >> 16)) * vv.y
        + bf2f((unsigned short)ua.y) * vv.z + bf2f((unsigned short)(ua.y >> 16)) * vv.w;
    r1 += bf2f((unsigned short)ub.x) * vv.x + bf2f((unsigned short)(ub.x >> 16)) * vv.y
        + bf2f((unsigned short)ub.y) * vv.z + bf2f((unsigned short)(ub.y >> 16)) * vv.w;
    r2 += bf2f((unsigned short)uc.x) * vv.x + bf2f((unsigned short)(uc.x >> 16)) * vv.y
        + bf2f((unsigned short)uc.y) * vv.z + bf2f((unsigned short)(uc.y >> 16)) * vv.w;
  }
  float bb = db[0];
  ros[n * 2] = r0 + bb;  ros[n * 2 + 1] = r1 + bb;
  rosa[n * 2] = r0 + bb; rosa[n * 2 + 1] = r2 + bb;
}

// ===================== classifier (x1o bf16, x2o fp32) =====================
__global__ __launch_bounds__(128) void k_cls(
    const int* __restrict__ idx, const unsigned short* __restrict__ x1o,
    const float* __restrict__ x2o,
    const float* __restrict__ attt, const float* __restrict__ cw, const float* __restrict__ cb,
    float* __restrict__ lg) {
  int b = blockIdx.x;
  int r = threadIdx.x;
  if (r >= RR) return;
  int i1 = idx[b], i2 = idx[BQ + b];
  float a0 = attt[0], a1 = attt[1];
  float acc = cb[r];
  const uint2* q1 = (const uint2*)(x1o + (size_t)i1 * H1);
  const float4* q2 = (const float4*)(x2o + (size_t)i1 * H2);
  const uint2* q3 = (const uint2*)(x1o + (size_t)i2 * H1);
  const float4* q4 = (const float4*)(x2o + (size_t)i2 * H2);
#pragma unroll
  for (int j = 0; j < 16; ++j) {
    uint2 u = q1[j];
    float v0 = bf2f((unsigned short)u.x), v1 = bf2f((unsigned short)(u.x >> 16));
    float v2 = bf2f((unsigned short)u.y), v3 = bf2f((unsigned short)(u.y >> 16));
    acc = fmaf(a0 * v0, cw[(4 * j) * RR + r], acc);
    acc = fmaf(a0 * v1, cw[(4 * j + 1) * RR + r], acc);
    acc = fmaf(a0 * v2, cw[(4 * j + 2) * RR + r], acc);
    acc = fmaf(a0 * v3, cw[(4 * j + 3) * RR + r], acc);
  }
#pragma unroll
  for (int j = 0; j < H2 / 4; ++j) {
    float v[4]; *(float4*)v = q2[j];
#pragma unroll
    for (int t = 0; t < 4; ++t) acc = fmaf(a1 * v[t], cw[(H1 + 4 * j + t) * RR + r], acc);
  }
#pragma unroll
  for (int j = 0; j < 16; ++j) {
    uint2 u = q3[j];
    float v0 = bf2f((unsigned short)u.x), v1 = bf2f((unsigned short)(u.x >> 16));
    float v2 = bf2f((unsigned short)u.y), v3 = bf2f((unsigned short)(u.y >> 16));
    acc = fmaf(a0 * v0, cw[(96 + 4 * j) * RR + r], acc);
    acc = fmaf(a0 * v1, cw[(96 + 4 * j + 1) * RR + r], acc);
    acc = fmaf(a0 * v2, cw[(96 + 4 * j + 2) * RR + r], acc);
    acc = fmaf(a0 * v3, cw[(96 + 4 * j + 3) * RR + r], acc);
  }
#pragma unroll
  for (int j = 0; j < H2 / 4; ++j) {
    float v[4]; *(float4*)v = q4[j];
#pragma unroll
    for (int t = 0; t < 4; ++t) acc = fmaf(a1 * v[t], cw[(96 + H1 + 4 * j + t) * RR + r], acc);
  }
  lg[(size_t)b * RR + r] = acc;
}

// ===================== launch =====================
extern "C" void kernel_launch(void* const* d_in, const int* in_sizes, int n_in,
                              void* d_out, int out_size, void* d_ws, size_t ws_size,
                              hipStream_t stream) {
  const float* x_o  = (const float*)d_in[0];
  const float* x_a  = (const float*)d_in[1];
  const int*   ei   = (const int*)d_in[2];
  const int*   etA  = (const int*)d_in[3];
  const int*   etB  = (const int*)d_in[4];
  const int*   idx  = (const int*)d_in[5];
  const float* W1   = (const float*)d_in[6];
  const float* rt1  = (const float*)d_in[7];
  const float* b1   = (const float*)d_in[8];
  const float* W2   = (const float*)d_in[9];
  const float* rt2  = (const float*)d_in[10];
  const float* b2   = (const float*)d_in[11];
  const float* attt = (const float*)d_in[12];
  const float* dw   = (const float*)d_in[13];
  const float* db   = (const float*)d_in[14];
  const float* cw   = (const float*)d_in[15];
  const float* cb   = (const float*)d_in[16];

  const size_t NRp = 1300224;
  int* wsI      = (int*)d_ws;
  int* cntA     = wsI;                       // NRp
  int* cntB     = cntA + NRp;                // NRp
  int* binCntA  = cntB + NRp;                // NBPAD
  int* binCntB  = binCntA + NBPAD;           // NBPAD
  float* hacc   = (float*)(binCntB + NBPAD); // 32
  float* vbuf   = hacc + 32;                 // 32
  // --- end of memset region ---
  int* binStartA = (int*)(vbuf + 32);        // NBPAD
  int* binCurA   = binStartA + NBPAD;
  int* binStartB = binCurA + NBPAD;
  int* binCurB   = binStartB + NBPAD;
  int* mA        = binCurB + NBPAD;          // NE (src | dstLocal<<20)
  int* mB        = mA + NE;                  // NE
  float* ivA     = (float*)(mB + NE);        // NE
  float* ivB     = ivA + NE;                 // NE
  // bf16 region
  unsigned short* xo16    = (unsigned short*)(ivB + NE);   // NN*FF
  unsigned short* xa16    = xo16 + (size_t)NN * FF;
  unsigned short* x1o16   = xa16 + (size_t)NN * FF;        // NN*H1 x3
  unsigned short* x1a16   = x1o16 + (size_t)NN * H1;
  unsigned short* x1aa16  = x1a16 + (size_t)NN * H1;
  unsigned short* x2ob    = x1aa16 + (size_t)NN * H1;      // NN*H2 x3
  unsigned short* x2oab   = x2ob + (size_t)NN * H2;
  unsigned short* x2oaab  = x2oab + (size_t)NN * H2;
  unsigned short* rootO16 = x2oaab + (size_t)NN * H2;      // NN*H1 x2
  unsigned short* rootA16 = rootO16 + (size_t)NN * H1;
  unsigned short* r2o16   = rootA16 + (size_t)NN * H1;     // NN*H2 x3
  unsigned short* r2a16   = r2o16 + (size_t)NN * H2;
  unsigned short* r2aa16  = r2a16 + (size_t)NN * H2;
  unsigned short* W1f     = r2aa16 + (size_t)NN * H2;      // RR*16*64*8
  unsigned short* W2f     = W1f + (size_t)RR * 16 * 64 * 8;

  float* outF   = (float*)d_out;
  float* o_log  = outF;
  float* o_ros  = outF + (size_t)BQ * RR;
  float* o_rosa = o_ros + (size_t)NN * 2;
  float* o_x2o  = o_rosa + (size_t)NN * 2;

  hipMemsetAsync(wsI, 0, (2 * NRp + 2 * NBPAD + 64) * sizeof(int), stream);

  // prep (independent of hist chain)
  k_cvt2<<<(2 * NN * FF / 8 + 255) / 256, 256, 0, stream>>>(
      (const float4*)x_o, (const float4*)x_a, (uint4*)xo16, (uint4*)xa16, NN * FF / 8);
  k_wprep1<<<RR, 256, 0, stream>>>(W1, W1f);
  k_wprep2<<<RR, 256, 0, stream>>>(W2, W2f);
  k_root1<<<(NN * H1) / 256, 256, 0, stream>>>(x_o, x_a, rt1, b1, rootO16, rootA16);

  k_hist<<<(NE + 255) / 256, 256, 0, stream>>>(ei, etA, etB, cntA, cntB, binCntA, binCntB);
  k_prefixB<<<1, 256, 0, stream>>>(binCntA, binStartA, binCurA, binCntB, binStartB, binCurB);
  k_scatter2<<<(NE + 255) / 256, 256, 0, stream>>>(ei, etA, etB, cntA, cntB,
                                                   binCurA, binCurB, mA, ivA, mB, ivB);

  k_edgeL1<2><<<NBLK, 512, 0, stream>>>(mA, ivA, binStartA, binCntA, W1f,
                                        xo16, xa16, rootO16, rootA16, x1o16, x1a16);
  k_edgeL1<1><<<NBLK, 512, 0, stream>>>(mB, ivB, binStartB, binCntB, W1f,
                                        xo16, nullptr, rootO16, nullptr, x1aa16, nullptr);

  k_root2x3<<<(NN * H2 + 255) / 256, 256, 0, stream>>>(x1o16, x1a16, x1aa16, rt2, b2,
                                                       r2o16, r2a16, r2aa16);
  k_edgeL2<2><<<NBLK, 512, 0, stream>>>(mA, ivA, binStartA, binCntA, W2f,
                                        x1o16, x1a16, r2o16, r2a16, x2ob, x2oab, o_x2o);
  k_edgeL2<1><<<NBLK, 512, 0, stream>>>(mB, ivB, binStartB, binCntB, W2f,
                                        x1aa16, nullptr, r2aa16, nullptr, x2oaab, nullptr,
                                        nullptr);

  k_colsum<<<128, 256, 0, stream>>>(o_x2o, hacc);
  k_disc<<<1, 64, 0, stream>>>(hacc, dw, vbuf);
  k_ret<<<(NN + 255) / 256, 256, 0, stream>>>(x2ob, x2oab, x2oaab, vbuf, db, o_ros, o_rosa);
  k_cls<<<BQ, 128, 0, stream>>>(idx, x1o16, o_x2o, attt, cw, cb, o_log);
}